// Round 14
// baseline (624.891 us; speedup 1.0000x reference)
//
#include <hip/hip_runtime.h>
#include <hip/hip_bf16.h>
#include <math.h>

#define BATCH   2
#define LSEQ    16384
#define BLTOK   (BATCH*LSEQ)    // 32768 tokens
#define DMODEL  128
#define DINNER  256
#define DSTATE  64
#define NHEADS  4
#define HEADDIM 64
#define DPROJ   644             // logical cols of in_proj
#define PROJS   648             // padded row stride of projb
#define CCH     384             // DINNER + 2*DSTATE
#define KCONV   4
#define QCH     64
#define NCHUNK  (LSEQ/QCH)      // 256
#define NLAYER  4
#define FC1N    512

typedef __bf16 bf16x8 __attribute__((ext_vector_type(8)));
typedef float  f32x4  __attribute__((ext_vector_type(4)));

__device__ __forceinline__ float silu_f(float x){ return x / (1.f + __expf(-x)); }

__device__ __forceinline__ unsigned short f2bfu(float f){
    union {float f; uint32_t u;} v; v.f = f;
    return (unsigned short)((v.u + 0x7FFF + ((v.u>>16)&1)) >> 16);
}
__device__ __forceinline__ float bfu2f(unsigned short u){
    union {uint32_t u; float f;} v; v.u = ((uint32_t)u)<<16;
    return v.f;
}
// swizzled byte address, 128B-row LDS tile (16B-chunk XOR)
__device__ __forceinline__ int swza(int r, int bytecol){
    return r*128 + ((((bytecol)>>4)^(r&7))<<4) + ((bytecol)&15);
}

// ---------------- weights convert: in/f1/f2 row layout [N][K]; out packed MFMA fragments ----------------
__global__ __launch_bounds__(256) void wconv_all_kernel(
    const float* __restrict__ in_proj, const float* __restrict__ out_proj,
    const float* __restrict__ fc1_w,  const float* __restrict__ fc2_w,
    unsigned short* __restrict__ wt_in, unsigned short* __restrict__ wt_out,
    unsigned short* __restrict__ wt_f1, unsigned short* __restrict__ wt_f2)
{
    const int PER = 90112 + 32768 + 65536 + 32768;   // 221184
    int id = blockIdx.x*256 + threadIdx.x;
    int layer = id / PER;
    if (layer >= NLAYER) return;
    int rem = id - layer*PER;
    if (rem < 90112){                                 // in: [704][128] <- [128][644]
        int n = rem >> 7, k = rem & 127;
        float f = (n < DPROJ) ? in_proj[(size_t)layer*DMODEL*DPROJ + (size_t)k*DPROJ + n] : 0.f;
        wt_in[(size_t)layer*90112 + rem] = f2bfu(f);
    } else if (rem < 122880){                         // out_proj: packed fragments, NT=8, KT=8
        int e = rem - 90112;
        int j = e&7, lane = (e>>3)&63, tile = e>>9;
        int kt = tile & 7, ct = tile >> 3;
        int n = ct*16 + (lane&15);
        int k = kt*32 + ((lane>>4)<<3) + j;
        wt_out[(size_t)layer*32768 + e] = f2bfu(out_proj[(size_t)layer*DINNER*DMODEL + (size_t)k*DMODEL + n]);
    } else if (rem < 188416){                         // f1: [512][128] <- [128][512]
        int r2 = rem - 122880;
        int n = r2 >> 7, k = r2 & 127;
        wt_f1[(size_t)layer*65536 + r2] = f2bfu(fc1_w[(size_t)layer*DMODEL*FC1N + (size_t)k*FC1N + n]);
    } else {                                          // f2: [128][256] <- [256][128]
        int r2 = rem - 188416;
        int n = r2 >> 8, k = r2 & 255;
        wt_f2[(size_t)layer*32768 + r2] = f2bfu(fc2_w[(size_t)layer*DINNER*DMODEL + (size_t)k*DMODEL + n]);
    }
}

// ---------------- LayerNorm (pre-loop only) ----------------
__global__ __launch_bounds__(256) void ln_kernel(const float* __restrict__ x,
    const float* __restrict__ w, const float* __restrict__ b, unsigned short* __restrict__ out)
{
    int row  = blockIdx.x*4 + (threadIdx.x>>6);
    int lane = threadIdx.x & 63;
    const float* xr = x + (size_t)row*DMODEL;
    float2 vv = *(const float2*)(xr + lane*2);
    float s = vv.x + vv.y;
    #pragma unroll
    for (int o=32;o;o>>=1) s += __shfl_xor(s,o);
    float mu = s * (1.f/DMODEL);
    float d0 = vv.x-mu, d1 = vv.y-mu;
    float q = d0*d0 + d1*d1;
    #pragma unroll
    for (int o=32;o;o>>=1) q += __shfl_xor(q,o);
    float inv = rsqrtf(q*(1.f/DMODEL) + 1e-5f);
    float2 ww = *(const float2*)(w + lane*2);
    float2 bb = *(const float2*)(b + lane*2);
    uint32_t pk = (uint32_t)f2bfu(d0*inv*ww.x + bb.x) | ((uint32_t)f2bfu(d1*inv*ww.y + bb.y)<<16);
    ((uint32_t*)(out + (size_t)row*DMODEL))[lane] = pk;
}

// ---------------- in_proj GEMM: bf16 cols<640 -> projb (stride PROJS), f32 dt -> dtb ----------------
__global__ __launch_bounds__(256) void gemm_inproj_kernel(
    const unsigned short* __restrict__ A, const unsigned short* __restrict__ Wt,
    unsigned short* __restrict__ Cb, float* __restrict__ dtb)
{
    __shared__ __align__(16) char lds[2*64*128*2];
    char* As = lds;
    char* Bs = lds + 64*128*2;
    const int tid = threadIdx.x;
    const int row0 = blockIdx.y*64, col0 = blockIdx.x*64;
    const int wave = tid>>6, lane = tid&63;
    const int wm = wave>>1, wn = wave&1;
    const int frow = lane&15, kgrp = lane>>4;
    f32x4 acc[2][2] = {{{0,0,0,0},{0,0,0,0}},{{0,0,0,0},{0,0,0,0}}};
    #pragma unroll
    for (int p=0;p<4;p++){
        int e = tid + p*256;
        int r = e>>4, kc = e&15;
        uint4 av = *(const uint4*)(A  + (size_t)(row0+r)*DMODEL + kc*8);
        uint4 bv = *(const uint4*)(Wt + (size_t)(col0+r)*DMODEL + kc*8);
        int sw = (kc ^ (r&7))*16;
        *(uint4*)(As + r*256 + sw) = av;
        *(uint4*)(Bs + r*256 + sw) = bv;
    }
    __syncthreads();
    #pragma unroll
    for (int ks=0; ks<4; ks++){
        int kc = ks*4 + kgrp;
        int ra0 = wm*32 + frow, ra1 = ra0 + 16;
        int rb0 = wn*32 + frow, rb1 = rb0 + 16;
        bf16x8 a0 = *(const bf16x8*)(As + ra0*256 + ((kc ^ (ra0&7))*16));
        bf16x8 a1 = *(const bf16x8*)(As + ra1*256 + ((kc ^ (ra1&7))*16));
        bf16x8 b0 = *(const bf16x8*)(Bs + rb0*256 + ((kc ^ (rb0&7))*16));
        bf16x8 b1 = *(const bf16x8*)(Bs + rb1*256 + ((kc ^ (rb1&7))*16));
        acc[0][0] = __builtin_amdgcn_mfma_f32_16x16x32_bf16(a0,b0,acc[0][0],0,0,0);
        acc[0][1] = __builtin_amdgcn_mfma_f32_16x16x32_bf16(a0,b1,acc[0][1],0,0,0);
        acc[1][0] = __builtin_amdgcn_mfma_f32_16x16x32_bf16(a1,b0,acc[1][0],0,0,0);
        acc[1][1] = __builtin_amdgcn_mfma_f32_16x16x32_bf16(a1,b1,acc[1][1],0,0,0);
    }
    const int crow = (lane>>4)*4, ccol = lane&15;
    #pragma unroll
    for (int fm=0;fm<2;fm++)
    #pragma unroll
    for (int fn=0;fn<2;fn++){
        int gc = col0 + wn*32 + fn*16 + ccol;
        #pragma unroll
        for (int r=0;r<4;r++){
            int gr = row0 + wm*32 + fm*16 + crow + r;
            if (gc < 640)      Cb [(size_t)gr*PROJS + gc]   = f2bfu(acc[fm][fn][r]);
            else if (gc < 644) dtb[(size_t)gr*4 + (gc-640)] = acc[fm][fn][r];
        }
    }
}

// ---------------- causal conv K=4 + bias + silu: LDS-staged, bf16 in/out ----------------
__global__ __launch_bounds__(256) void conv_kernel(
    const unsigned short* __restrict__ projb,
    const float* __restrict__ cw, const float* __restrict__ cb,
    unsigned short* __restrict__ xBCb, unsigned short* __restrict__ Cbuf)
{
    __shared__ __align__(16) char raw[35*768];
    __shared__ float wsm[4*384];
    __shared__ float bsm[384];
    const int tid = threadIdx.x;
    const size_t tok0 = (size_t)blockIdx.x * 32;
    const int l0 = (int)(tok0 & (LSEQ-1));
    for (int e = tid; e < 35*48; e += 256){
        int r = e / 48, cg = e - r*48;
        uint4 v = {0,0,0,0};
        if (l0 + r - 3 >= 0)
            v = *(const uint4*)(projb + (tok0 + r - 3)*PROJS + 256 + cg*8);
        *(uint4*)(raw + r*768 + cg*16) = v;
    }
    for (int e = tid; e < 1536; e += 256) wsm[e] = cw[e];
    for (int e = tid; e < 384;  e += 256) bsm[e] = cb[e];
    __syncthreads();
    const int cg = tid & 63;
    if (cg >= 48) return;
    const int sb = (tid >> 6) * 8;
    float wk[4][8], bu[8];
    #pragma unroll
    for (int k=0;k<4;k++)
        #pragma unroll
        for (int u=0;u<8;u++) wk[k][u] = wsm[k*384 + cg*8 + u];
    #pragma unroll
    for (int u=0;u<8;u++) bu[u] = bsm[cg*8 + u];
    #pragma unroll
    for (int i=0;i<8;i++){
        int s = sb + i;
        float acc[8];
        #pragma unroll
        for (int u=0;u<8;u++) acc[u] = bu[u];
        #pragma unroll
        for (int k=0;k<4;k++){
            const unsigned short* tap = (const unsigned short*)(raw + (s+k)*768 + cg*16);
            #pragma unroll
            for (int u=0;u<8;u++) acc[u] += bfu2f(tap[u]) * wk[k][u];
        }
        unsigned short o[8];
        #pragma unroll
        for (int u=0;u<8;u++) o[u] = f2bfu(silu_f(acc[u]));
        uint4 pk;
        ((uint32_t*)&pk)[0] = (uint32_t)o[0] | ((uint32_t)o[1]<<16);
        ((uint32_t*)&pk)[1] = (uint32_t)o[2] | ((uint32_t)o[3]<<16);
        ((uint32_t*)&pk)[2] = (uint32_t)o[4] | ((uint32_t)o[5]<<16);
        ((uint32_t*)&pk)[3] = (uint32_t)o[6] | ((uint32_t)o[7]<<16);
        *(uint4*)(xBCb + (tok0+s)*CCH + cg*8) = pk;
        if (cg >= 40) *(uint4*)(Cbuf + (tok0+s)*DSTATE + (cg-40)*8) = pk;
    }
}

// ---------------- scan part A: head-merged intra-chunk; vectorized X staging; bf16 states out ----------------
__global__ __launch_bounds__(256) void scan_intra_kernel(
    const unsigned short* __restrict__ xBCb, const float* __restrict__ dtb,
    const float* __restrict__ dt_bias, const float* __restrict__ A_log,
    const float* __restrict__ Dp,
    unsigned short* __restrict__ yb, unsigned short* __restrict__ statesb,
    float* __restrict__ Sbuf)
{
    const int c = blockIdx.x, b = blockIdx.y;
    const int tid = threadIdx.x;
    __shared__ __align__(16) char Xt[4][64*128];
    __shared__ __align__(16) char Bl[64*128];
    __shared__ __align__(16) char Cl[64*128];
    __shared__ __align__(16) char Bt[64*128];
    __shared__ __align__(16) char Bw[64*128];
    __shared__ __align__(16) char Gl[64*128];
    __shared__ float Ss[4][QCH], dts[4][QCH], wsd[4][QCH];
    const size_t tok0 = (size_t)b*LSEQ + (size_t)c*QCH;

    const int wv = tid>>6, j = tid&63;
    // X staging: vectorized uint4 loads (wave wv stages head wv), rotated transpose-scatter
    #pragma unroll
    for (int i=0;i<8;i++){
        int s = i*8 + (j>>3);
        int p0 = (j&7)*8;
        uint4 v = *(const uint4*)(xBCb + (tok0+s)*CCH + wv*HEADDIM + p0);
        const unsigned short* vu = (const unsigned short*)&v;
        #pragma unroll
        for (int u=0;u<8;u++){
            int uu = (u + (j>>3)) & 7;
            *(unsigned short*)(Xt[wv] + swza(p0+uu, s*2)) = vu[uu];
        }
    }
    #pragma unroll
    for (int i=0;i<2;i++){
        int e = tid + i*256;
        int s = e>>3, cg = e&7;
        uint4 bv = *(const uint4*)(xBCb + (tok0+s)*CCH + 256 + cg*8);
        uint4 cv = *(const uint4*)(xBCb + (tok0+s)*CCH + 320 + cg*8);
        *(uint4*)(Bl + swza(s, cg*16)) = bv;
        *(uint4*)(Cl + swza(s, cg*16)) = cv;
    }
    #pragma unroll
    for (int i=0;i<16;i++){
        int s = wv*16 + i;
        *(unsigned short*)(Bt + swza(j, s*2)) = xBCb[(tok0+s)*CCH + 256 + j];
    }
    {
        float v = dtb[(tok0+j)*4 + wv] + dt_bias[wv];
        float dtv = (v > 20.f) ? v : log1pf(__expf(v));
        float val = -dtv * __expf(A_log[wv]);
        #pragma unroll
        for (int o=1;o<64;o<<=1){ float nv = __shfl_up(val,o); if (j >= o) val += nv; }
        float last = __shfl(val, 63);
        Ss [wv][j] = val;
        dts[wv][j] = dtv;
        wsd[wv][j] = __expf(last - val) * dtv;
        Sbuf[(size_t)(b*NHEADS+wv)*LSEQ + (size_t)c*QCH + j] = val;
    }
    __syncthreads();

    const int wm = wv>>1, wn = wv&1;
    const int frow = j&15, kg = j>>4;
    const int crow = (j>>4)*4, ccol = j&15;

    f32x4 accG[2][2] = {{{0,0,0,0},{0,0,0,0}},{{0,0,0,0},{0,0,0,0}}};
    #pragma unroll
    for (int ks=0; ks<2; ks++){
        int kc = ks*4 + kg;
        int ra0 = wm*32+frow, ra1 = ra0+16, rb0 = wn*32+frow, rb1 = rb0+16;
        bf16x8 a0 = *(const bf16x8*)(Cl + ra0*128 + ((kc^(ra0&7))<<4));
        bf16x8 a1 = *(const bf16x8*)(Cl + ra1*128 + ((kc^(ra1&7))<<4));
        bf16x8 b0 = *(const bf16x8*)(Bl + rb0*128 + ((kc^(rb0&7))<<4));
        bf16x8 b1 = *(const bf16x8*)(Bl + rb1*128 + ((kc^(rb1&7))<<4));
        accG[0][0] = __builtin_amdgcn_mfma_f32_16x16x32_bf16(a0,b0,accG[0][0],0,0,0);
        accG[0][1] = __builtin_amdgcn_mfma_f32_16x16x32_bf16(a0,b1,accG[0][1],0,0,0);
        accG[1][0] = __builtin_amdgcn_mfma_f32_16x16x32_bf16(a1,b0,accG[1][0],0,0,0);
        accG[1][1] = __builtin_amdgcn_mfma_f32_16x16x32_bf16(a1,b1,accG[1][1],0,0,0);
    }

    for (int h=0; h<NHEADS; h++){
        #pragma unroll
        for (int fm=0;fm<2;fm++)
        #pragma unroll
        for (int fn=0;fn<2;fn++){
            int s_ = wn*32 + fn*16 + ccol;
            #pragma unroll
            for (int r=0;r<4;r++){
                int t_ = wm*32 + fm*16 + crow + r;
                float g = (s_ <= t_) ? accG[fm][fn][r]*__expf(Ss[h][t_]-Ss[h][s_])*dts[h][s_] : 0.f;
                *(unsigned short*)(Gl + swza(t_, s_*2)) = f2bfu(g);
            }
        }
        #pragma unroll
        for (int i=0;i<16;i++){
            int n = wv*16 + i;
            float bv = bfu2f(*(const unsigned short*)(Bt + swza(n, j*2)));
            *(unsigned short*)(Bw + swza(n, j*2)) = f2bfu(bv * wsd[h][j]);
        }
        __syncthreads();
        f32x4 accY[2][2] = {{{0,0,0,0},{0,0,0,0}},{{0,0,0,0},{0,0,0,0}}};
        f32x4 accS[2][2] = {{{0,0,0,0},{0,0,0,0}},{{0,0,0,0},{0,0,0,0}}};
        const char* Xh = Xt[h];
        #pragma unroll
        for (int ks=0; ks<2; ks++){
            int kc = ks*4 + kg;
            int ra0 = wm*32+frow, ra1 = ra0+16, rb0 = wn*32+frow, rb1 = rb0+16;
            bf16x8 g0 = *(const bf16x8*)(Gl + ra0*128 + ((kc^(ra0&7))<<4));
            bf16x8 g1 = *(const bf16x8*)(Gl + ra1*128 + ((kc^(ra1&7))<<4));
            bf16x8 xb0= *(const bf16x8*)(Xh + rb0*128 + ((kc^(rb0&7))<<4));
            bf16x8 xb1= *(const bf16x8*)(Xh + rb1*128 + ((kc^(rb1&7))<<4));
            bf16x8 xa0= *(const bf16x8*)(Xh + ra0*128 + ((kc^(ra0&7))<<4));
            bf16x8 xa1= *(const bf16x8*)(Xh + ra1*128 + ((kc^(ra1&7))<<4));
            bf16x8 w0 = *(const bf16x8*)(Bw + rb0*128 + ((kc^(rb0&7))<<4));
            bf16x8 w1 = *(const bf16x8*)(Bw + rb1*128 + ((kc^(rb1&7))<<4));
            accY[0][0] = __builtin_amdgcn_mfma_f32_16x16x32_bf16(g0,xb0,accY[0][0],0,0,0);
            accY[0][1] = __builtin_amdgcn_mfma_f32_16x16x32_bf16(g0,xb1,accY[0][1],0,0,0);
            accY[1][0] = __builtin_amdgcn_mfma_f32_16x16x32_bf16(g1,xb0,accY[1][0],0,0,0);
            accY[1][1] = __builtin_amdgcn_mfma_f32_16x16x32_bf16(g1,xb1,accY[1][1],0,0,0);
            accS[0][0] = __builtin_amdgcn_mfma_f32_16x16x32_bf16(xa0,w0,accS[0][0],0,0,0);
            accS[0][1] = __builtin_amdgcn_mfma_f32_16x16x32_bf16(xa0,w1,accS[0][1],0,0,0);
            accS[1][0] = __builtin_amdgcn_mfma_f32_16x16x32_bf16(xa1,w0,accS[1][0],0,0,0);
            accS[1][1] = __builtin_amdgcn_mfma_f32_16x16x32_bf16(xa1,w1,accS[1][1],0,0,0);
        }
        float dpv = Dp[h];
        size_t sb = ((size_t)(b*NHEADS+h)*NCHUNK + c)*HEADDIM*DSTATE;
        #pragma unroll
        for (int fm=0;fm<2;fm++)
        #pragma unroll
        for (int fn=0;fn<2;fn++){
            int colj = wn*32 + fn*16 + ccol;
            #pragma unroll
            for (int r=0;r<4;r++){
                int rowi = wm*32 + fm*16 + crow + r;
                float xh = bfu2f(*(const unsigned short*)(Xh + swza(colj, rowi*2)));
                yb[(tok0+rowi)*DINNER + h*HEADDIM + colj] = f2bfu(accY[fm][fn][r] + dpv*xh);
                statesb[sb + rowi*DSTATE + colj] = f2bfu(accS[fm][fn][r]);
            }
        }
        __syncthreads();
    }
}

// ---------------- scan part B: inter-chunk recurrence (bf16 states in); emits packed Hp ----------------
__global__ __launch_bounds__(256) void scan_inter_kernel(const unsigned short* __restrict__ statesb,
    const float* __restrict__ Sbuf, unsigned short* __restrict__ Hp)
{
    int bh   = blockIdx.x >> 4;
    int part = blockIdx.x & 15;
    int pn   = part*256 + threadIdx.x;
    __shared__ float dec[NCHUNK];
    for (int c = threadIdx.x; c < NCHUNK; c += 256)
        dec[c] = __expf(Sbuf[(size_t)bh*LSEQ + (size_t)c*QCH + QCH-1]);
    __syncthreads();
    const int p = pn>>6, n = pn&63;
    const int tr = p>>4, frow = p&15;
    const int ks = n>>5, kg = (n>>3)&3, jj = n&7;
    const int subofs = ((tr*2+ks)*64 + (kg*16+frow))*8 + jj;
    float hh = 0.f;
    const size_t baseF = (size_t)bh*NCHUNK*4096 + pn;
    const size_t baseH = (size_t)bh*NCHUNK*4096 + subofs;
    for (int c0=0; c0<NCHUNK; c0+=16){
        float loc[16];
        #pragma unroll
        for (int k=0;k<16;k++) loc[k] = bfu2f(statesb[baseF + (size_t)(c0+k)*4096]);
        #pragma unroll
        for (int k=0;k<16;k++){
            Hp[baseH + (size_t)(c0+k)*4096] = f2bfu(hh);
            hh = dec[c0+k]*hh + loc[k];
        }
    }
}

// ---------------- apply + gate + out_proj + residual + LN2: 32 tokens/block, grid (NCHUNK*2, BATCH) ----------------
__global__ __launch_bounds__(256) void apply_out_kernel(
    const unsigned short* __restrict__ y1b, const unsigned short* __restrict__ Hp,
    const unsigned short* __restrict__ Cbuf, const unsigned short* __restrict__ projb,
    const float* __restrict__ Sbuf, const unsigned short* __restrict__ Wp,
    float* __restrict__ bufx, unsigned short* __restrict__ lnb,
    const float* __restrict__ lnw, const float* __restrict__ lnbias)
{
    const int c2 = blockIdx.x, b = blockIdx.y;
    const int c = c2 >> 1;
    const int tid = threadIdx.x;
    __shared__ __align__(16) char SH[32*132*4];   // 16896: Yl (first 16KB), Ot overlays after GEMM
    __shared__ __align__(16) char Cl[32*128];     // 4KB
    __shared__ float Es[4][32];                   // 0.5KB
    const size_t tok0 = (size_t)b*LSEQ + (size_t)c2*32;

    #pragma unroll
    for (int i=0;i<4;i++){
        int e = tid + i*256;
        int r = e>>5, ch = e&31;
        uint4 v = *(const uint4*)(y1b + (tok0+r)*DINNER + ch*8);
        *(uint4*)(SH + r*512 + ((ch ^ (r&7))<<4)) = v;
    }
    {
        int r = tid>>3, q = tid&7;
        uint4 cv = *(const uint4*)(Cbuf + (tok0+r)*DSTATE + q*8);
        *(uint4*)(Cl + swza(r, q*16)) = cv;
    }
    if (tid < 128){
        int h = tid>>5, t = tid&31;
        Es[h][t] = __expf(Sbuf[(size_t)(b*NHEADS+h)*LSEQ + (size_t)c2*32 + t]);
    }
    __syncthreads();                                  // barrier 1

    const int wv = tid>>6, lane = tid&63;
    const int wm = wv>>1, wn = wv&1;
    const int frow = lane&15, kg = lane>>4;
    const int crow = (lane>>4)*4, ccol = lane&15;

    // apply: acc = C[32x64] @ H^T, H fragments coalesced direct from packed global
    for (int h=0;h<NHEADS;h++){
        const unsigned short* Hb = Hp + ((size_t)(b*NHEADS+h)*NCHUNK + c)*4096;
        f32x4 acc[2] = {{0,0,0,0},{0,0,0,0}};
        #pragma unroll
        for (int ks=0; ks<2; ks++){
            int kc = ks*4 + kg;
            int ra = wm*16 + frow;
            bf16x8 a  = *(const bf16x8*)(Cl + ra*128 + ((kc^(ra&7))<<4));
            bf16x8 b0 = *(const bf16x8*)(Hb + (size_t)((wn*4 + ks    )*64 + lane)*8);
            bf16x8 b1 = *(const bf16x8*)(Hb + (size_t)((wn*4 + 2 + ks)*64 + lane)*8);
            acc[0] = __builtin_amdgcn_mfma_f32_16x16x32_bf16(a,b0,acc[0],0,0,0);
            acc[1] = __builtin_amdgcn_mfma_f32_16x16x32_bf16(a,b1,acc[1],0,0,0);
        }
        #pragma unroll
        for (int fn=0;fn<2;fn++){
            int p = wn*32 + fn*16 + ccol;
            int bc = (h*64+p)*2;
            #pragma unroll
            for (int r=0;r<4;r++){
                int t = wm*16 + crow + r;
                int addr = t*512 + (((bc>>4) ^ (t&7))<<4) + (bc&15);
                float y1 = bfu2f(*(const unsigned short*)(SH+addr));
                *(unsigned short*)(SH+addr) = f2bfu(y1 + Es[h][t]*acc[fn][r]);
            }
        }
    }
    __syncthreads();                                  // barrier 2
    // gate pass: vectorized y * silu(z), coalesced z loads
    #pragma unroll
    for (int i=0;i<4;i++){
        int e = tid + i*256;
        int r = e>>5, ch = e&31;
        int addr = r*512 + ((ch ^ (r&7))<<4);
        uint4 yv = *(const uint4*)(SH + addr);
        uint4 zv = *(const uint4*)(projb + (tok0+r)*PROJS + ch*8);
        const unsigned short* yu = (const unsigned short*)&yv;
        const unsigned short* zu = (const unsigned short*)&zv;
        unsigned short o[8];
        #pragma unroll
        for (int u=0;u<8;u++) o[u] = f2bfu(bfu2f(yu[u]) * silu_f(bfu2f(zu[u])));
        uint4 pk;
        ((uint32_t*)&pk)[0] = (uint32_t)o[0] | ((uint32_t)o[1]<<16);
        ((uint32_t*)&pk)[1] = (uint32_t)o[2] | ((uint32_t)o[3]<<16);
        ((uint32_t*)&pk)[2] = (uint32_t)o[4] | ((uint32_t)o[5]<<16);
        ((uint32_t*)&pk)[3] = (uint32_t)o[6] | ((uint32_t)o[7]<<16);
        *(uint4*)(SH + addr) = pk;
    }
    __syncthreads();                                  // barrier 3

    // GEMM: out[32][128] = Y[32][256] @ Wout, W fragments direct from packed global (NT=8,KT=8)
    f32x4 og[4] = {{0,0,0,0},{0,0,0,0},{0,0,0,0},{0,0,0,0}};
    #pragma unroll
    for (int kt=0;kt<8;kt++){
        int ch0 = kt*4 + kg;
        int ra = wm*16 + frow;
        bf16x8 a = *(const bf16x8*)(SH + ra*512 + ((ch0 ^ (ra&7))<<4));
        #pragma unroll
        for (int fn=0;fn<4;fn++){
            bf16x8 bb = *(const bf16x8*)(Wp + (size_t)(((wn*4+fn)*8 + kt)*64 + lane)*8);
            og[fn] = __builtin_amdgcn_mfma_f32_16x16x32_bf16(a,bb,og[fn],0,0,0);
        }
    }
    __syncthreads();                                  // barrier 4: Yl dead -> Ot overlay
    float* Ot = (float*)SH;
    #pragma unroll
    for (int fn=0;fn<4;fn++){
        int gc = wn*64 + fn*16 + ccol;
        #pragma unroll
        for (int r=0;r<4;r++){
            int t = wm*16 + crow + r;
            size_t idx = (tok0+t)*DMODEL + gc;
            float v = og[fn][r] + bufx[idx];
            bufx[idx] = v;
            Ot[t*132 + gc] = v;
        }
    }
    __syncthreads();                                  // barrier 5
    {
        float w0 = lnw[lane*2], w1 = lnw[lane*2+1];
        float b0 = lnbias[lane*2], b1 = lnbias[lane*2+1];
        for (int r=0;r<8;r++){
            int row = wv*8 + r;
            float v0 = Ot[row*132 + lane*2], v1 = Ot[row*132 + lane*2+1];
            float s = v0+v1, q = v0*v0+v1*v1;
            #pragma unroll
            for (int o=32;o;o>>=1){ s += __shfl_xor(s,o); q += __shfl_xor(q,o); }
            float mu = s*(1.f/DMODEL);
            float inv = rsqrtf(q*(1.f/DMODEL) - mu*mu + 1e-5f);
            uint32_t pk = (uint32_t)f2bfu((v0-mu)*inv*w0 + b0) |
                          ((uint32_t)f2bfu((v1-mu)*inv*w1 + b1)<<16);
            ((uint32_t*)(lnb + (tok0+row)*DMODEL))[lane] = pk;
        }
    }
}

// ---------------- fc1 + GLU fused (R7-proven) ----------------
__global__ __launch_bounds__(256) void fc1glu_kernel(
    const unsigned short* __restrict__ A, const unsigned short* __restrict__ Wt,
    const float* __restrict__ bias, unsigned short* __restrict__ out)
{
    __shared__ __align__(16) char lds[3*64*128*2];
    char* As = lds;
    char* B1 = lds + 64*256;
    char* B2 = lds + 2*64*256;
    const int tid = threadIdx.x;
    const int row0 = blockIdx.y*64, col0 = blockIdx.x*64;
    const int wave = tid>>6, lane = tid&63;
    const int wm = wave>>1, wn = wave&1;
    const int frow = lane&15, kgrp = lane>>4;
    f32x4 acc1[2][2] = {{{0,0,0,0},{0,0,0,0}},{{0,0,0,0},{0,0,0,0}}};
    f32x4 acc2[2][2] = {{{0,0,0,0},{0,0,0,0}},{{0,0,0,0},{0,0,0,0}}};
    #pragma unroll
    for (int p=0;p<4;p++){
        int e = tid + p*256;
        int r = e>>4, kc = e&15;
        uint4 av = *(const uint4*)(A  + (size_t)(row0+r)*DMODEL + kc*8);
        uint4 b1 = *(const uint4*)(Wt + (size_t)(col0+r)*DMODEL + kc*8);
        uint4 b2 = *(const uint4*)(Wt + (size_t)(256+col0+r)*DMODEL + kc*8);
        int sw = (kc ^ (r&7))*16;
        *(uint4*)(As + r*256 + sw) = av;
        *(uint4*)(B1 + r*256 + sw) = b1;
        *(uint4*)(B2 + r*256 + sw) = b2;
    }
    __syncthreads();
    #pragma unroll
    for (int ks=0; ks<4; ks++){
        int kc = ks*4 + kgrp;
        int ra0 = wm*32 + frow, ra1 = ra0 + 16;
        int rb0 = wn*32 + frow, rb1 = rb0 + 16;
        bf16x8 a0 = *(const bf16x8*)(As + ra0*256 + ((kc ^ (ra0&7))*16));
        bf16x8 a1 = *(const bf16x8*)(As + ra1*256 + ((kc ^ (ra1&7))*16));
        bf16x8 p0 = *(const bf16x8*)(B1 + rb0*256 + ((kc ^ (rb0&7))*16));
        bf16x8 p1 = *(const bf16x8*)(B1 + rb1*256 + ((kc ^ (rb1&7))*16));
        bf16x8 q0 = *(const bf16x8*)(B2 + rb0*256 + ((kc ^ (rb0&7))*16));
        bf16x8 q1 = *(const bf16x8*)(B2 + rb1*256 + ((kc ^ (rb1&7))*16));
        acc1[0][0] = __builtin_amdgcn_mfma_f32_16x16x32_bf16(a0,p0,acc1[0][0],0,0,0);
        acc1[0][1] = __builtin_amdgcn_mfma_f32_16x16x32_bf16(a0,p1,acc1[0][1],0,0,0);
        acc1[1][0] = __builtin_amdgcn_mfma_f32_16x16x32_bf16(a1,p0,acc1[1][0],0,0,0);
        acc1[1][1] = __builtin_amdgcn_mfma_f32_16x16x32_bf16(a1,p1,acc1[1][1],0,0,0);
        acc2[0][0] = __builtin_amdgcn_mfma_f32_16x16x32_bf16(a0,q0,acc2[0][0],0,0,0);
        acc2[0][1] = __builtin_amdgcn_mfma_f32_16x16x32_bf16(a0,q1,acc2[0][1],0,0,0);
        acc2[1][0] = __builtin_amdgcn_mfma_f32_16x16x32_bf16(a1,q0,acc2[1][0],0,0,0);
        acc2[1][1] = __builtin_amdgcn_mfma_f32_16x16x32_bf16(a1,q1,acc2[1][1],0,0,0);
    }
    const int crow = (lane>>4)*4, ccol = lane&15;
    #pragma unroll
    for (int fm=0;fm<2;fm++)
    #pragma unroll
    for (int fn=0;fn<2;fn++){
        int gc = col0 + wn*32 + fn*16 + ccol;
        float b1 = bias[gc], b2 = bias[256+gc];
        #pragma unroll
        for (int r=0;r<4;r++){
            int gr = row0 + wm*32 + fm*16 + crow + r;
            float h1 = acc1[fm][fn][r] + b1;
            float h2 = acc2[fm][fn][r] + b2;
            out[(size_t)gr*DINNER + gc] = f2bfu(silu_f(h1)*h2);
        }
    }
}

// ---------------- fc2 + residual + LN1(next) fused (R7-proven) ----------------
__global__ __launch_bounds__(256) void fc2ln_kernel(
    const unsigned short* __restrict__ A, const unsigned short* __restrict__ Wt,
    const float* __restrict__ bias, float* __restrict__ bufx,
    unsigned short* __restrict__ lnb,
    const float* __restrict__ lnw, const float* __restrict__ lnbias, const int doLN)
{
    __shared__ __align__(16) char SH[64*256 + 128*256];
    char* Al = SH;
    char* Wl = SH + 16384;
    float* Ot = (float*)SH;
    const int tid = threadIdx.x;
    const size_t tok0 = (size_t)blockIdx.x*64;
    const int wv = tid>>6, lane = tid&63;
    const int wm = wv>>1, wn = wv&1;
    const int frow = lane&15, kg = lane>>4;
    const int crow = (lane>>4)*4, ccol = lane&15;
    f32x4 og[2][4] = {{{0,0,0,0},{0,0,0,0},{0,0,0,0},{0,0,0,0}},
                      {{0,0,0,0},{0,0,0,0},{0,0,0,0},{0,0,0,0}}};
    for (int k0=0;k0<256;k0+=128){
        __syncthreads();
        #pragma unroll
        for (int i=0;i<4;i++){
            int e = tid + i*256;
            int r = e>>4, kc = e&15;
            uint4 av = *(const uint4*)(A + (tok0+r)*DINNER + k0 + kc*8);
            *(uint4*)(Al + r*256 + ((kc ^ (r&7))<<4)) = av;
        }
        #pragma unroll
        for (int i=0;i<8;i++){
            int e = tid + i*256;
            int r = e>>4, kc = e&15;
            uint4 w4 = *(const uint4*)(Wt + (size_t)r*256 + k0 + kc*8);
            *(uint4*)(Wl + r*256 + ((kc ^ (r&7))<<4)) = w4;
        }
        __syncthreads();
        #pragma unroll
        for (int ks=0;ks<4;ks++){
            int kc = ks*4 + kg;
            int ra0 = wm*32+frow, ra1 = ra0+16;
            bf16x8 a0 = *(const bf16x8*)(Al + ra0*256 + ((kc ^ (ra0&7))<<4));
            bf16x8 a1 = *(const bf16x8*)(Al + ra1*256 + ((kc ^ (ra1&7))<<4));
            #pragma unroll
            for (int fn=0;fn<4;fn++){
                int rb = wn*64 + fn*16 + frow;
                bf16x8 bb = *(const bf16x8*)(Wl + rb*256 + ((kc ^ (rb&7))<<4));
                og[0][fn] = __builtin_amdgcn_mfma_f32_16x16x32_bf16(a0,bb,og[0][fn],0,0,0);
                og[1][fn] = __builtin_amdgcn_mfma_f32_16x16x32_bf16(a1,bb,og[1][fn],0,0,0);
            }
        }
    }
    __syncthreads();
    #pragma unroll
    for (int fm=0;fm<2;fm++)
    #pragma unroll
    for (int fn=0;fn<4;fn++){
        int gc = wn*64 + fn*16 + ccol;
        float bv = bias[gc];
        #pragma unroll
        for (int r=0;r<4;r++){
            int t = wm*32 + fm*16 + crow + r;
            size_t idx = (tok0+t)*DMODEL + gc;
            float v = og[fm][fn][r] + bv + bufx[idx];
            bufx[idx] = v;
            Ot[t*132 + gc] = v;
        }
    }
    if (doLN){
        __syncthreads();
        float w0 = lnw[lane*2], w1 = lnw[lane*2+1];
        float b0 = lnbias[lane*2], b1 = lnbias[lane*2+1];
        for (int r=0;r<16;r++){
            int row = wv*16 + r;
            float v0 = Ot[row*132 + lane*2], v1 = Ot[row*132 + lane*2+1];
            float s = v0+v1, q = v0*v0+v1*v1;
            #pragma unroll
            for (int o=32;o;o>>=1){ s += __shfl_xor(s,o); q += __shfl_xor(q,o); }
            float mu = s*(1.f/DMODEL);
            float inv = rsqrtf(q*(1.f/DMODEL) - mu*mu + 1e-5f);
            uint32_t pk = (uint32_t)f2bfu((v0-mu)*inv*w0 + b0) |
                          ((uint32_t)f2bfu((v1-mu)*inv*w1 + b1)<<16);
            ((uint32_t*)(lnb + (tok0+row)*DMODEL))[lane] = pk;
        }
    }
}

extern "C" void kernel_launch(void* const* d_in, const int* in_sizes, int n_in,
                              void* d_out, int out_size, void* d_ws, size_t ws_size,
                              hipStream_t stream)
{
    const float* x_in    = (const float*)d_in[0];
    const float* ln1_w   = (const float*)d_in[1];
    const float* ln1_b   = (const float*)d_in[2];
    const float* ln2_w   = (const float*)d_in[3];
    const float* ln2_b   = (const float*)d_in[4];
    const float* in_proj = (const float*)d_in[5];
    const float* conv_w  = (const float*)d_in[6];
    const float* conv_b  = (const float*)d_in[7];
    const float* dt_bias = (const float*)d_in[8];
    const float* A_log   = (const float*)d_in[9];
    const float* Dp      = (const float*)d_in[10];
    const float* out_proj= (const float*)d_in[11];
    const float* fc1_w   = (const float*)d_in[12];
    const float* fc1_b   = (const float*)d_in[13];
    const float* fc2_w   = (const float*)d_in[14];
    const float* fc2_b   = (const float*)d_in[15];

    float* ws = (float*)d_ws;
    float* buf_x    = ws;
    float* dtb      = buf_x  + (size_t)BLTOK*DMODEL;
    float* Sbuf     = dtb    + (size_t)BLTOK*4;
    unsigned short* projb  = (unsigned short*)(Sbuf + (size_t)BATCH*NHEADS*LSEQ);
    unsigned short* actb   = projb  + (size_t)BLTOK*PROJS;
    unsigned short* lnb    = actb   + (size_t)BLTOK*DINNER;
    unsigned short* cbuf   = lnb    + (size_t)BLTOK*DMODEL;
    unsigned short* xBCb   = cbuf   + (size_t)BLTOK*DSTATE;
    unsigned short* statesb= xBCb   + (size_t)BLTOK*CCH;
    unsigned short* Hp     = statesb+ (size_t)BATCH*NHEADS*NCHUNK*HEADDIM*DSTATE;
    unsigned short* wt_in  = Hp     + (size_t)BATCH*NHEADS*NCHUNK*HEADDIM*DSTATE;
    unsigned short* wt_out = wt_in  + (size_t)NLAYER*90112;
    unsigned short* wt_f1  = wt_out + (size_t)NLAYER*32768;
    unsigned short* wt_f2  = wt_f1  + (size_t)NLAYER*65536;

    hipMemcpyAsync(buf_x, x_in, (size_t)BLTOK*DMODEL*sizeof(float),
                   hipMemcpyDeviceToDevice, stream);

    wconv_all_kernel<<<(NLAYER*221184+255)/256,256,0,stream>>>(
        in_proj, out_proj, fc1_w, fc2_w, wt_in, wt_out, wt_f1, wt_f2);

    ln_kernel<<<BLTOK/4,256,0,stream>>>(buf_x, ln1_w, ln1_b, lnb);

    for (int i=0;i<NLAYER;i++){
        gemm_inproj_kernel<<<dim3(11, BLTOK/64),256,0,stream>>>(
            lnb, wt_in + (size_t)i*90112, projb, dtb);
        conv_kernel<<<BLTOK/32,256,0,stream>>>(
            projb, conv_w+(size_t)i*KCONV*CCH, conv_b+(size_t)i*CCH, xBCb, cbuf);
        scan_intra_kernel<<<dim3(NCHUNK, BATCH),256,0,stream>>>(
            xBCb, dtb, dt_bias+i*NHEADS, A_log+i*NHEADS, Dp+i*NHEADS,
            actb, statesb, Sbuf);
        scan_inter_kernel<<<BATCH*NHEADS*16,256,0,stream>>>(statesb, Sbuf, Hp);
        apply_out_kernel<<<dim3(NCHUNK*2, BATCH),256,0,stream>>>(
            actb, Hp, cbuf, projb, Sbuf, wt_out + (size_t)i*32768,
            buf_x, lnb, ln2_w+i*DMODEL, ln2_b+i*DMODEL);
        fc1glu_kernel<<<dim3(4, BLTOK/64),256,0,stream>>>(
            lnb, wt_f1 + (size_t)i*65536, fc1_b+(size_t)i*FC1N, actb);
        fc2ln_kernel<<<BLTOK/64,256,0,stream>>>(
            actb, wt_f2 + (size_t)i*32768, fc2_b+i*DMODEL, buf_x, lnb,
            ln1_w+(i+1 < NLAYER ? (i+1)*DMODEL : 0),
            ln1_b+(i+1 < NLAYER ? (i+1)*DMODEL : 0),
            (i+1 < NLAYER) ? 1 : 0);
    }
    hipMemcpyAsync(d_out, buf_x, (size_t)BLTOK*DMODEL*sizeof(float),
                   hipMemcpyDeviceToDevice, stream);
}

// Round 15
// 523.708 us; speedup vs baseline: 1.1932x; 1.1932x over previous
//
#include <hip/hip_runtime.h>
#include <hip/hip_bf16.h>
#include <math.h>

#define BATCH   2
#define LSEQ    16384
#define BLTOK   (BATCH*LSEQ)    // 32768 tokens
#define DMODEL  128
#define DINNER  256
#define DSTATE  64
#define NHEADS  4
#define HEADDIM 64
#define DPROJ   644             // logical cols of in_proj
#define PROJS   648             // padded row stride of projb
#define CCH     384             // DINNER + 2*DSTATE
#define KCONV   4
#define QCH     64
#define NCHUNK  (LSEQ/QCH)      // 256
#define NLAYER  4
#define FC1N    512

typedef __bf16 bf16x8 __attribute__((ext_vector_type(8)));
typedef float  f32x4  __attribute__((ext_vector_type(4)));

__device__ __forceinline__ float silu_f(float x){ return x / (1.f + __expf(-x)); }

__device__ __forceinline__ unsigned short f2bfu(float f){
    union {float f; uint32_t u;} v; v.f = f;
    return (unsigned short)((v.u + 0x7FFF + ((v.u>>16)&1)) >> 16);
}
__device__ __forceinline__ float bfu2f(unsigned short u){
    union {uint32_t u; float f;} v; v.u = ((uint32_t)u)<<16;
    return v.f;
}
// swizzled byte address, 128B-row LDS tile (16B-chunk XOR)
__device__ __forceinline__ int swza(int r, int bytecol){
    return r*128 + ((((bytecol)>>4)^(r&7))<<4) + ((bytecol)&15);
}

// ---------------- weights convert: in/f1/f2 row layout [N][K]; out packed MFMA fragments ----------------
__global__ __launch_bounds__(256) void wconv_all_kernel(
    const float* __restrict__ in_proj, const float* __restrict__ out_proj,
    const float* __restrict__ fc1_w,  const float* __restrict__ fc2_w,
    unsigned short* __restrict__ wt_in, unsigned short* __restrict__ wt_out,
    unsigned short* __restrict__ wt_f1, unsigned short* __restrict__ wt_f2)
{
    const int PER = 90112 + 32768 + 65536 + 32768;   // 221184
    int id = blockIdx.x*256 + threadIdx.x;
    int layer = id / PER;
    if (layer >= NLAYER) return;
    int rem = id - layer*PER;
    if (rem < 90112){                                 // in: [704][128] <- [128][644]
        int n = rem >> 7, k = rem & 127;
        float f = (n < DPROJ) ? in_proj[(size_t)layer*DMODEL*DPROJ + (size_t)k*DPROJ + n] : 0.f;
        wt_in[(size_t)layer*90112 + rem] = f2bfu(f);
    } else if (rem < 122880){                         // out_proj: packed fragments, NT=8, KT=8
        int e = rem - 90112;
        int j = e&7, lane = (e>>3)&63, tile = e>>9;
        int kt = tile & 7, ct = tile >> 3;
        int n = ct*16 + (lane&15);
        int k = kt*32 + ((lane>>4)<<3) + j;
        wt_out[(size_t)layer*32768 + e] = f2bfu(out_proj[(size_t)layer*DINNER*DMODEL + (size_t)k*DMODEL + n]);
    } else if (rem < 188416){                         // f1: [512][128] <- [128][512]
        int r2 = rem - 122880;
        int n = r2 >> 7, k = r2 & 127;
        wt_f1[(size_t)layer*65536 + r2] = f2bfu(fc1_w[(size_t)layer*DMODEL*FC1N + (size_t)k*FC1N + n]);
    } else {                                          // f2: [128][256] <- [256][128]
        int r2 = rem - 188416;
        int n = r2 >> 8, k = r2 & 255;
        wt_f2[(size_t)layer*32768 + r2] = f2bfu(fc2_w[(size_t)layer*DINNER*DMODEL + (size_t)k*DMODEL + n]);
    }
}

// ---------------- LayerNorm (pre-loop only) ----------------
__global__ __launch_bounds__(256) void ln_kernel(const float* __restrict__ x,
    const float* __restrict__ w, const float* __restrict__ b, unsigned short* __restrict__ out)
{
    int row  = blockIdx.x*4 + (threadIdx.x>>6);
    int lane = threadIdx.x & 63;
    const float* xr = x + (size_t)row*DMODEL;
    float2 vv = *(const float2*)(xr + lane*2);
    float s = vv.x + vv.y;
    #pragma unroll
    for (int o=32;o;o>>=1) s += __shfl_xor(s,o);
    float mu = s * (1.f/DMODEL);
    float d0 = vv.x-mu, d1 = vv.y-mu;
    float q = d0*d0 + d1*d1;
    #pragma unroll
    for (int o=32;o;o>>=1) q += __shfl_xor(q,o);
    float inv = rsqrtf(q*(1.f/DMODEL) + 1e-5f);
    float2 ww = *(const float2*)(w + lane*2);
    float2 bb = *(const float2*)(b + lane*2);
    uint32_t pk = (uint32_t)f2bfu(d0*inv*ww.x + bb.x) | ((uint32_t)f2bfu(d1*inv*ww.y + bb.y)<<16);
    ((uint32_t*)(out + (size_t)row*DMODEL))[lane] = pk;
}

// ---------------- in_proj GEMM: bf16 cols<640 -> projb (stride PROJS), f32 dt -> dtb ----------------
__global__ __launch_bounds__(256) void gemm_inproj_kernel(
    const unsigned short* __restrict__ A, const unsigned short* __restrict__ Wt,
    unsigned short* __restrict__ Cb, float* __restrict__ dtb)
{
    __shared__ __align__(16) char lds[2*64*128*2];
    char* As = lds;
    char* Bs = lds + 64*128*2;
    const int tid = threadIdx.x;
    const int row0 = blockIdx.y*64, col0 = blockIdx.x*64;
    const int wave = tid>>6, lane = tid&63;
    const int wm = wave>>1, wn = wave&1;
    const int frow = lane&15, kgrp = lane>>4;
    f32x4 acc[2][2] = {{{0,0,0,0},{0,0,0,0}},{{0,0,0,0},{0,0,0,0}}};
    #pragma unroll
    for (int p=0;p<4;p++){
        int e = tid + p*256;
        int r = e>>4, kc = e&15;
        uint4 av = *(const uint4*)(A  + (size_t)(row0+r)*DMODEL + kc*8);
        uint4 bv = *(const uint4*)(Wt + (size_t)(col0+r)*DMODEL + kc*8);
        int sw = (kc ^ (r&7))*16;
        *(uint4*)(As + r*256 + sw) = av;
        *(uint4*)(Bs + r*256 + sw) = bv;
    }
    __syncthreads();
    #pragma unroll
    for (int ks=0; ks<4; ks++){
        int kc = ks*4 + kgrp;
        int ra0 = wm*32 + frow, ra1 = ra0 + 16;
        int rb0 = wn*32 + frow, rb1 = rb0 + 16;
        bf16x8 a0 = *(const bf16x8*)(As + ra0*256 + ((kc ^ (ra0&7))*16));
        bf16x8 a1 = *(const bf16x8*)(As + ra1*256 + ((kc ^ (ra1&7))*16));
        bf16x8 b0 = *(const bf16x8*)(Bs + rb0*256 + ((kc ^ (rb0&7))*16));
        bf16x8 b1 = *(const bf16x8*)(Bs + rb1*256 + ((kc ^ (rb1&7))*16));
        acc[0][0] = __builtin_amdgcn_mfma_f32_16x16x32_bf16(a0,b0,acc[0][0],0,0,0);
        acc[0][1] = __builtin_amdgcn_mfma_f32_16x16x32_bf16(a0,b1,acc[0][1],0,0,0);
        acc[1][0] = __builtin_amdgcn_mfma_f32_16x16x32_bf16(a1,b0,acc[1][0],0,0,0);
        acc[1][1] = __builtin_amdgcn_mfma_f32_16x16x32_bf16(a1,b1,acc[1][1],0,0,0);
    }
    const int crow = (lane>>4)*4, ccol = lane&15;
    #pragma unroll
    for (int fm=0;fm<2;fm++)
    #pragma unroll
    for (int fn=0;fn<2;fn++){
        int gc = col0 + wn*32 + fn*16 + ccol;
        #pragma unroll
        for (int r=0;r<4;r++){
            int gr = row0 + wm*32 + fm*16 + crow + r;
            if (gc < 640)      Cb [(size_t)gr*PROJS + gc]   = f2bfu(acc[fm][fn][r]);
            else if (gc < 644) dtb[(size_t)gr*4 + (gc-640)] = acc[fm][fn][r];
        }
    }
}

// ---------------- causal conv K=4 + bias + silu: LDS-staged, bf16 in/out ----------------
__global__ __launch_bounds__(256) void conv_kernel(
    const unsigned short* __restrict__ projb,
    const float* __restrict__ cw, const float* __restrict__ cb,
    unsigned short* __restrict__ xBCb, unsigned short* __restrict__ Cbuf)
{
    __shared__ __align__(16) char raw[35*768];
    __shared__ float wsm[4*384];
    __shared__ float bsm[384];
    const int tid = threadIdx.x;
    const size_t tok0 = (size_t)blockIdx.x * 32;
    const int l0 = (int)(tok0 & (LSEQ-1));
    for (int e = tid; e < 35*48; e += 256){
        int r = e / 48, cg = e - r*48;
        uint4 v = {0,0,0,0};
        if (l0 + r - 3 >= 0)
            v = *(const uint4*)(projb + (tok0 + r - 3)*PROJS + 256 + cg*8);
        *(uint4*)(raw + r*768 + cg*16) = v;
    }
    for (int e = tid; e < 1536; e += 256) wsm[e] = cw[e];
    for (int e = tid; e < 384;  e += 256) bsm[e] = cb[e];
    __syncthreads();
    const int cg = tid & 63;
    if (cg >= 48) return;
    const int sb = (tid >> 6) * 8;
    float wk[4][8], bu[8];
    #pragma unroll
    for (int k=0;k<4;k++)
        #pragma unroll
        for (int u=0;u<8;u++) wk[k][u] = wsm[k*384 + cg*8 + u];
    #pragma unroll
    for (int u=0;u<8;u++) bu[u] = bsm[cg*8 + u];
    #pragma unroll
    for (int i=0;i<8;i++){
        int s = sb + i;
        float acc[8];
        #pragma unroll
        for (int u=0;u<8;u++) acc[u] = bu[u];
        #pragma unroll
        for (int k=0;k<4;k++){
            const unsigned short* tap = (const unsigned short*)(raw + (s+k)*768 + cg*16);
            #pragma unroll
            for (int u=0;u<8;u++) acc[u] += bfu2f(tap[u]) * wk[k][u];
        }
        unsigned short o[8];
        #pragma unroll
        for (int u=0;u<8;u++) o[u] = f2bfu(silu_f(acc[u]));
        uint4 pk;
        ((uint32_t*)&pk)[0] = (uint32_t)o[0] | ((uint32_t)o[1]<<16);
        ((uint32_t*)&pk)[1] = (uint32_t)o[2] | ((uint32_t)o[3]<<16);
        ((uint32_t*)&pk)[2] = (uint32_t)o[4] | ((uint32_t)o[5]<<16);
        ((uint32_t*)&pk)[3] = (uint32_t)o[6] | ((uint32_t)o[7]<<16);
        *(uint4*)(xBCb + (tok0+s)*CCH + cg*8) = pk;
        if (cg >= 40) *(uint4*)(Cbuf + (tok0+s)*DSTATE + (cg-40)*8) = pk;
    }
}

// ---------------- scan part A: head-merged intra-chunk (R7-proven) ----------------
__global__ __launch_bounds__(256) void scan_intra_kernel(
    const unsigned short* __restrict__ xBCb, const float* __restrict__ dtb,
    const float* __restrict__ dt_bias, const float* __restrict__ A_log,
    const float* __restrict__ Dp,
    unsigned short* __restrict__ yb, float* __restrict__ states, float* __restrict__ Sbuf)
{
    const int c = blockIdx.x, b = blockIdx.y;
    const int tid = threadIdx.x;
    __shared__ __align__(16) char Xt[4][64*128];
    __shared__ __align__(16) char Bl[64*128];
    __shared__ __align__(16) char Cl[64*128];
    __shared__ __align__(16) char Bt[64*128];
    __shared__ __align__(16) char Bw[64*128];
    __shared__ __align__(16) char Gl[64*128];
    __shared__ float Ss[4][QCH], dts[4][QCH], wsd[4][QCH];
    const size_t tok0 = (size_t)b*LSEQ + (size_t)c*QCH;

    const int wv = tid>>6, j = tid&63;
    #pragma unroll 16
    for (int s=0;s<64;s++){
        unsigned short xv = xBCb[(tok0+s)*CCH + wv*HEADDIM + j];
        *(unsigned short*)(Xt[wv] + swza(j, s*2)) = xv;
    }
    #pragma unroll
    for (int i=0;i<2;i++){
        int e = tid + i*256;
        int s = e>>3, cg = e&7;
        uint4 bv = *(const uint4*)(xBCb + (tok0+s)*CCH + 256 + cg*8);
        uint4 cv = *(const uint4*)(xBCb + (tok0+s)*CCH + 320 + cg*8);
        *(uint4*)(Bl + swza(s, cg*16)) = bv;
        *(uint4*)(Cl + swza(s, cg*16)) = cv;
    }
    #pragma unroll
    for (int i=0;i<16;i++){
        int s = wv*16 + i;
        *(unsigned short*)(Bt + swza(j, s*2)) = xBCb[(tok0+s)*CCH + 256 + j];
    }
    {
        float v = dtb[(tok0+j)*4 + wv] + dt_bias[wv];
        float dtv = (v > 20.f) ? v : log1pf(__expf(v));
        float val = -dtv * __expf(A_log[wv]);
        #pragma unroll
        for (int o=1;o<64;o<<=1){ float nv = __shfl_up(val,o); if (j >= o) val += nv; }
        float last = __shfl(val, 63);
        Ss [wv][j] = val;
        dts[wv][j] = dtv;
        wsd[wv][j] = __expf(last - val) * dtv;
        Sbuf[(size_t)(b*NHEADS+wv)*LSEQ + (size_t)c*QCH + j] = val;
    }
    __syncthreads();

    const int wm = wv>>1, wn = wv&1;
    const int frow = j&15, kg = j>>4;
    const int crow = (j>>4)*4, ccol = j&15;

    f32x4 accG[2][2] = {{{0,0,0,0},{0,0,0,0}},{{0,0,0,0},{0,0,0,0}}};
    #pragma unroll
    for (int ks=0; ks<2; ks++){
        int kc = ks*4 + kg;
        int ra0 = wm*32+frow, ra1 = ra0+16, rb0 = wn*32+frow, rb1 = rb0+16;
        bf16x8 a0 = *(const bf16x8*)(Cl + ra0*128 + ((kc^(ra0&7))<<4));
        bf16x8 a1 = *(const bf16x8*)(Cl + ra1*128 + ((kc^(ra1&7))<<4));
        bf16x8 b0 = *(const bf16x8*)(Bl + rb0*128 + ((kc^(rb0&7))<<4));
        bf16x8 b1 = *(const bf16x8*)(Bl + rb1*128 + ((kc^(rb1&7))<<4));
        accG[0][0] = __builtin_amdgcn_mfma_f32_16x16x32_bf16(a0,b0,accG[0][0],0,0,0);
        accG[0][1] = __builtin_amdgcn_mfma_f32_16x16x32_bf16(a0,b1,accG[0][1],0,0,0);
        accG[1][0] = __builtin_amdgcn_mfma_f32_16x16x32_bf16(a1,b0,accG[1][0],0,0,0);
        accG[1][1] = __builtin_amdgcn_mfma_f32_16x16x32_bf16(a1,b1,accG[1][1],0,0,0);
    }

    for (int h=0; h<NHEADS; h++){
        #pragma unroll
        for (int fm=0;fm<2;fm++)
        #pragma unroll
        for (int fn=0;fn<2;fn++){
            int s_ = wn*32 + fn*16 + ccol;
            #pragma unroll
            for (int r=0;r<4;r++){
                int t_ = wm*32 + fm*16 + crow + r;
                float g = (s_ <= t_) ? accG[fm][fn][r]*__expf(Ss[h][t_]-Ss[h][s_])*dts[h][s_] : 0.f;
                *(unsigned short*)(Gl + swza(t_, s_*2)) = f2bfu(g);
            }
        }
        #pragma unroll
        for (int i=0;i<16;i++){
            int n = wv*16 + i;
            float bv = bfu2f(*(const unsigned short*)(Bt + swza(n, j*2)));
            *(unsigned short*)(Bw + swza(n, j*2)) = f2bfu(bv * wsd[h][j]);
        }
        __syncthreads();
        f32x4 accY[2][2] = {{{0,0,0,0},{0,0,0,0}},{{0,0,0,0},{0,0,0,0}}};
        f32x4 accS[2][2] = {{{0,0,0,0},{0,0,0,0}},{{0,0,0,0},{0,0,0,0}}};
        const char* Xh = Xt[h];
        #pragma unroll
        for (int ks=0; ks<2; ks++){
            int kc = ks*4 + kg;
            int ra0 = wm*32+frow, ra1 = ra0+16, rb0 = wn*32+frow, rb1 = rb0+16;
            bf16x8 g0 = *(const bf16x8*)(Gl + ra0*128 + ((kc^(ra0&7))<<4));
            bf16x8 g1 = *(const bf16x8*)(Gl + ra1*128 + ((kc^(ra1&7))<<4));
            bf16x8 xb0= *(const bf16x8*)(Xh + rb0*128 + ((kc^(rb0&7))<<4));
            bf16x8 xb1= *(const bf16x8*)(Xh + rb1*128 + ((kc^(rb1&7))<<4));
            bf16x8 xa0= *(const bf16x8*)(Xh + ra0*128 + ((kc^(ra0&7))<<4));
            bf16x8 xa1= *(const bf16x8*)(Xh + ra1*128 + ((kc^(ra1&7))<<4));
            bf16x8 w0 = *(const bf16x8*)(Bw + rb0*128 + ((kc^(rb0&7))<<4));
            bf16x8 w1 = *(const bf16x8*)(Bw + rb1*128 + ((kc^(rb1&7))<<4));
            accY[0][0] = __builtin_amdgcn_mfma_f32_16x16x32_bf16(g0,xb0,accY[0][0],0,0,0);
            accY[0][1] = __builtin_amdgcn_mfma_f32_16x16x32_bf16(g0,xb1,accY[0][1],0,0,0);
            accY[1][0] = __builtin_amdgcn_mfma_f32_16x16x32_bf16(g1,xb0,accY[1][0],0,0,0);
            accY[1][1] = __builtin_amdgcn_mfma_f32_16x16x32_bf16(g1,xb1,accY[1][1],0,0,0);
            accS[0][0] = __builtin_amdgcn_mfma_f32_16x16x32_bf16(xa0,w0,accS[0][0],0,0,0);
            accS[0][1] = __builtin_amdgcn_mfma_f32_16x16x32_bf16(xa0,w1,accS[0][1],0,0,0);
            accS[1][0] = __builtin_amdgcn_mfma_f32_16x16x32_bf16(xa1,w0,accS[1][0],0,0,0);
            accS[1][1] = __builtin_amdgcn_mfma_f32_16x16x32_bf16(xa1,w1,accS[1][1],0,0,0);
        }
        float dpv = Dp[h];
        size_t sb = ((size_t)(b*NHEADS+h)*NCHUNK + c)*HEADDIM*DSTATE;
        #pragma unroll
        for (int fm=0;fm<2;fm++)
        #pragma unroll
        for (int fn=0;fn<2;fn++){
            int colj = wn*32 + fn*16 + ccol;
            #pragma unroll
            for (int r=0;r<4;r++){
                int rowi = wm*32 + fm*16 + crow + r;
                float xh = bfu2f(*(const unsigned short*)(Xh + swza(colj, rowi*2)));
                yb[(tok0+rowi)*DINNER + h*HEADDIM + colj] = f2bfu(accY[fm][fn][r] + dpv*xh);
                states[sb + rowi*DSTATE + colj] = accS[fm][fn][r];
            }
        }
        __syncthreads();
    }
}

// ---------------- scan part B: inter-chunk recurrence; emits bf16 states in MFMA-fragment order ----------------
__global__ __launch_bounds__(256) void scan_inter_kernel(const float* __restrict__ states,
    const float* __restrict__ Sbuf, unsigned short* __restrict__ Hp)
{
    int bh   = blockIdx.x >> 4;
    int part = blockIdx.x & 15;
    int pn   = part*256 + threadIdx.x;
    __shared__ float dec[NCHUNK];
    for (int c = threadIdx.x; c < NCHUNK; c += 256)
        dec[c] = __expf(Sbuf[(size_t)bh*LSEQ + (size_t)c*QCH + QCH-1]);
    __syncthreads();
    const int p = pn>>6, n = pn&63;
    const int tr = p>>4, frow = p&15;
    const int ks = n>>5, kg = (n>>3)&3, jj = n&7;
    const int subofs = ((tr*2+ks)*64 + (kg*16+frow))*8 + jj;
    float hh = 0.f;
    const size_t baseF = (size_t)bh*NCHUNK*4096 + pn;
    const size_t baseH = (size_t)bh*NCHUNK*4096 + subofs;
    for (int c0=0; c0<NCHUNK; c0+=16){
        float loc[16];
        #pragma unroll
        for (int k=0;k<16;k++) loc[k] = states[baseF + (size_t)(c0+k)*4096];
        #pragma unroll
        for (int k=0;k<16;k++){
            Hp[baseH + (size_t)(c0+k)*4096] = f2bfu(hh);
            hh = dec[c0+k]*hh + loc[k];
        }
    }
}

// ---------------- apply + gate + out_proj + residual + LN2: 32 tokens/block, grid (NCHUNK*2, BATCH) ----------------
__global__ __launch_bounds__(256) void apply_out_kernel(
    const unsigned short* __restrict__ y1b, const unsigned short* __restrict__ Hp,
    const unsigned short* __restrict__ Cbuf, const unsigned short* __restrict__ projb,
    const float* __restrict__ Sbuf, const unsigned short* __restrict__ Wp,
    float* __restrict__ bufx, unsigned short* __restrict__ lnb,
    const float* __restrict__ lnw, const float* __restrict__ lnbias)
{
    const int c2 = blockIdx.x, b = blockIdx.y;
    const int c = c2 >> 1;
    const int tid = threadIdx.x;
    __shared__ __align__(16) char SH[32*132*4];   // 16896: Yl (first 16KB), Ot overlays after GEMM
    __shared__ __align__(16) char Cl[32*128];     // 4KB
    __shared__ float Es[4][32];                   // 0.5KB
    const size_t tok0 = (size_t)b*LSEQ + (size_t)c2*32;

    #pragma unroll
    for (int i=0;i<4;i++){
        int e = tid + i*256;
        int r = e>>5, ch = e&31;
        uint4 v = *(const uint4*)(y1b + (tok0+r)*DINNER + ch*8);
        *(uint4*)(SH + r*512 + ((ch ^ (r&7))<<4)) = v;
    }
    {
        int r = tid>>3, q = tid&7;
        uint4 cv = *(const uint4*)(Cbuf + (tok0+r)*DSTATE + q*8);
        *(uint4*)(Cl + swza(r, q*16)) = cv;
    }
    if (tid < 128){
        int h = tid>>5, t = tid&31;
        Es[h][t] = __expf(Sbuf[(size_t)(b*NHEADS+h)*LSEQ + (size_t)c2*32 + t]);
    }
    __syncthreads();                                  // barrier 1

    const int wv = tid>>6, lane = tid&63;
    const int wm = wv>>1, wn = wv&1;
    const int frow = lane&15, kg = lane>>4;
    const int crow = (lane>>4)*4, ccol = lane&15;

    // apply: acc = C[32x64] @ H^T, H fragments coalesced direct from packed global
    for (int h=0;h<NHEADS;h++){
        const unsigned short* Hb = Hp + ((size_t)(b*NHEADS+h)*NCHUNK + c)*4096;
        f32x4 acc[2] = {{0,0,0,0},{0,0,0,0}};
        #pragma unroll
        for (int ks=0; ks<2; ks++){
            int kc = ks*4 + kg;
            int ra = wm*16 + frow;
            bf16x8 a  = *(const bf16x8*)(Cl + ra*128 + ((kc^(ra&7))<<4));
            bf16x8 b0 = *(const bf16x8*)(Hb + (size_t)((wn*4 + ks    )*64 + lane)*8);
            bf16x8 b1 = *(const bf16x8*)(Hb + (size_t)((wn*4 + 2 + ks)*64 + lane)*8);
            acc[0] = __builtin_amdgcn_mfma_f32_16x16x32_bf16(a,b0,acc[0],0,0,0);
            acc[1] = __builtin_amdgcn_mfma_f32_16x16x32_bf16(a,b1,acc[1],0,0,0);
        }
        #pragma unroll
        for (int fn=0;fn<2;fn++){
            int p = wn*32 + fn*16 + ccol;
            int bc = (h*64+p)*2;
            #pragma unroll
            for (int r=0;r<4;r++){
                int t = wm*16 + crow + r;
                int addr = t*512 + (((bc>>4) ^ (t&7))<<4) + (bc&15);
                float y1 = bfu2f(*(const unsigned short*)(SH+addr));
                *(unsigned short*)(SH+addr) = f2bfu(y1 + Es[h][t]*acc[fn][r]);
            }
        }
    }
    __syncthreads();                                  // barrier 2
    // gate pass: vectorized y * silu(z), coalesced z loads
    #pragma unroll
    for (int i=0;i<4;i++){
        int e = tid + i*256;
        int r = e>>5, ch = e&31;
        int addr = r*512 + ((ch ^ (r&7))<<4);
        uint4 yv = *(const uint4*)(SH + addr);
        uint4 zv = *(const uint4*)(projb + (tok0+r)*PROJS + ch*8);
        const unsigned short* yu = (const unsigned short*)&yv;
        const unsigned short* zu = (const unsigned short*)&zv;
        unsigned short o[8];
        #pragma unroll
        for (int u=0;u<8;u++) o[u] = f2bfu(bfu2f(yu[u]) * silu_f(bfu2f(zu[u])));
        uint4 pk;
        ((uint32_t*)&pk)[0] = (uint32_t)o[0] | ((uint32_t)o[1]<<16);
        ((uint32_t*)&pk)[1] = (uint32_t)o[2] | ((uint32_t)o[3]<<16);
        ((uint32_t*)&pk)[2] = (uint32_t)o[4] | ((uint32_t)o[5]<<16);
        ((uint32_t*)&pk)[3] = (uint32_t)o[6] | ((uint32_t)o[7]<<16);
        *(uint4*)(SH + addr) = pk;
    }
    __syncthreads();                                  // barrier 3

    // GEMM: out[32][128] = Y[32][256] @ Wout, W fragments direct from packed global (NT=8,KT=8)
    f32x4 og[4] = {{0,0,0,0},{0,0,0,0},{0,0,0,0},{0,0,0,0}};
    #pragma unroll
    for (int kt=0;kt<8;kt++){
        int ch0 = kt*4 + kg;
        int ra = wm*16 + frow;
        bf16x8 a = *(const bf16x8*)(SH + ra*512 + ((ch0 ^ (ra&7))<<4));
        #pragma unroll
        for (int fn=0;fn<4;fn++){
            bf16x8 bb = *(const bf16x8*)(Wp + (size_t)(((wn*4+fn)*8 + kt)*64 + lane)*8);
            og[fn] = __builtin_amdgcn_mfma_f32_16x16x32_bf16(a,bb,og[fn],0,0,0);
        }
    }
    __syncthreads();                                  // barrier 4: Yl dead -> Ot overlay
    float* Ot = (float*)SH;
    #pragma unroll
    for (int fn=0;fn<4;fn++){
        int gc = wn*64 + fn*16 + ccol;
        #pragma unroll
        for (int r=0;r<4;r++){
            int t = wm*16 + crow + r;
            size_t idx = (tok0+t)*DMODEL + gc;
            float v = og[fn][r] + bufx[idx];
            bufx[idx] = v;
            Ot[t*132 + gc] = v;
        }
    }
    __syncthreads();                                  // barrier 5
    {
        float w0 = lnw[lane*2], w1 = lnw[lane*2+1];
        float b0 = lnbias[lane*2], b1 = lnbias[lane*2+1];
        for (int r=0;r<8;r++){
            int row = wv*8 + r;
            float v0 = Ot[row*132 + lane*2], v1 = Ot[row*132 + lane*2+1];
            float s = v0+v1, q = v0*v0+v1*v1;
            #pragma unroll
            for (int o=32;o;o>>=1){ s += __shfl_xor(s,o); q += __shfl_xor(q,o); }
            float mu = s*(1.f/DMODEL);
            float inv = rsqrtf(q*(1.f/DMODEL) - mu*mu + 1e-5f);
            uint32_t pk = (uint32_t)f2bfu((v0-mu)*inv*w0 + b0) |
                          ((uint32_t)f2bfu((v1-mu)*inv*w1 + b1)<<16);
            ((uint32_t*)(lnb + (tok0+row)*DMODEL))[lane] = pk;
        }
    }
}

// ---------------- fc1 + GLU fused (R7-proven) ----------------
__global__ __launch_bounds__(256) void fc1glu_kernel(
    const unsigned short* __restrict__ A, const unsigned short* __restrict__ Wt,
    const float* __restrict__ bias, unsigned short* __restrict__ out)
{
    __shared__ __align__(16) char lds[3*64*128*2];
    char* As = lds;
    char* B1 = lds + 64*256;
    char* B2 = lds + 2*64*256;
    const int tid = threadIdx.x;
    const int row0 = blockIdx.y*64, col0 = blockIdx.x*64;
    const int wave = tid>>6, lane = tid&63;
    const int wm = wave>>1, wn = wave&1;
    const int frow = lane&15, kgrp = lane>>4;
    f32x4 acc1[2][2] = {{{0,0,0,0},{0,0,0,0}},{{0,0,0,0},{0,0,0,0}}};
    f32x4 acc2[2][2] = {{{0,0,0,0},{0,0,0,0}},{{0,0,0,0},{0,0,0,0}}};
    #pragma unroll
    for (int p=0;p<4;p++){
        int e = tid + p*256;
        int r = e>>4, kc = e&15;
        uint4 av = *(const uint4*)(A  + (size_t)(row0+r)*DMODEL + kc*8);
        uint4 b1 = *(const uint4*)(Wt + (size_t)(col0+r)*DMODEL + kc*8);
        uint4 b2 = *(const uint4*)(Wt + (size_t)(256+col0+r)*DMODEL + kc*8);
        int sw = (kc ^ (r&7))*16;
        *(uint4*)(As + r*256 + sw) = av;
        *(uint4*)(B1 + r*256 + sw) = b1;
        *(uint4*)(B2 + r*256 + sw) = b2;
    }
    __syncthreads();
    #pragma unroll
    for (int ks=0; ks<4; ks++){
        int kc = ks*4 + kgrp;
        int ra0 = wm*32 + frow, ra1 = ra0 + 16;
        int rb0 = wn*32 + frow, rb1 = rb0 + 16;
        bf16x8 a0 = *(const bf16x8*)(As + ra0*256 + ((kc ^ (ra0&7))*16));
        bf16x8 a1 = *(const bf16x8*)(As + ra1*256 + ((kc ^ (ra1&7))*16));
        bf16x8 p0 = *(const bf16x8*)(B1 + rb0*256 + ((kc ^ (rb0&7))*16));
        bf16x8 p1 = *(const bf16x8*)(B1 + rb1*256 + ((kc ^ (rb1&7))*16));
        bf16x8 q0 = *(const bf16x8*)(B2 + rb0*256 + ((kc ^ (rb0&7))*16));
        bf16x8 q1 = *(const bf16x8*)(B2 + rb1*256 + ((kc ^ (rb1&7))*16));
        acc1[0][0] = __builtin_amdgcn_mfma_f32_16x16x32_bf16(a0,p0,acc1[0][0],0,0,0);
        acc1[0][1] = __builtin_amdgcn_mfma_f32_16x16x32_bf16(a0,p1,acc1[0][1],0,0,0);
        acc1[1][0] = __builtin_amdgcn_mfma_f32_16x16x32_bf16(a1,p0,acc1[1][0],0,0,0);
        acc1[1][1] = __builtin_amdgcn_mfma_f32_16x16x32_bf16(a1,p1,acc1[1][1],0,0,0);
        acc2[0][0] = __builtin_amdgcn_mfma_f32_16x16x32_bf16(a0,q0,acc2[0][0],0,0,0);
        acc2[0][1] = __builtin_amdgcn_mfma_f32_16x16x32_bf16(a0,q1,acc2[0][1],0,0,0);
        acc2[1][0] = __builtin_amdgcn_mfma_f32_16x16x32_bf16(a1,q0,acc2[1][0],0,0,0);
        acc2[1][1] = __builtin_amdgcn_mfma_f32_16x16x32_bf16(a1,q1,acc2[1][1],0,0,0);
    }
    const int crow = (lane>>4)*4, ccol = lane&15;
    #pragma unroll
    for (int fm=0;fm<2;fm++)
    #pragma unroll
    for (int fn=0;fn<2;fn++){
        int gc = col0 + wn*32 + fn*16 + ccol;
        float b1 = bias[gc], b2 = bias[256+gc];
        #pragma unroll
        for (int r=0;r<4;r++){
            int gr = row0 + wm*32 + fm*16 + crow + r;
            float h1 = acc1[fm][fn][r] + b1;
            float h2 = acc2[fm][fn][r] + b2;
            out[(size_t)gr*DINNER + gc] = f2bfu(silu_f(h1)*h2);
        }
    }
}

// ---------------- fc2 + residual + LN1(next) fused (R7-proven) ----------------
__global__ __launch_bounds__(256) void fc2ln_kernel(
    const unsigned short* __restrict__ A, const unsigned short* __restrict__ Wt,
    const float* __restrict__ bias, float* __restrict__ bufx,
    unsigned short* __restrict__ lnb,
    const float* __restrict__ lnw, const float* __restrict__ lnbias, const int doLN)
{
    __shared__ __align__(16) char SH[64*256 + 128*256];
    char* Al = SH;
    char* Wl = SH + 16384;
    float* Ot = (float*)SH;
    const int tid = threadIdx.x;
    const size_t tok0 = (size_t)blockIdx.x*64;
    const int wv = tid>>6, lane = tid&63;
    const int wm = wv>>1, wn = wv&1;
    const int frow = lane&15, kg = lane>>4;
    const int crow = (lane>>4)*4, ccol = lane&15;
    f32x4 og[2][4] = {{{0,0,0,0},{0,0,0,0},{0,0,0,0},{0,0,0,0}},
                      {{0,0,0,0},{0,0,0,0},{0,0,0,0},{0,0,0,0}}};
    for (int k0=0;k0<256;k0+=128){
        __syncthreads();
        #pragma unroll
        for (int i=0;i<4;i++){
            int e = tid + i*256;
            int r = e>>4, kc = e&15;
            uint4 av = *(const uint4*)(A + (tok0+r)*DINNER + k0 + kc*8);
            *(uint4*)(Al + r*256 + ((kc ^ (r&7))<<4)) = av;
        }
        #pragma unroll
        for (int i=0;i<8;i++){
            int e = tid + i*256;
            int r = e>>4, kc = e&15;
            uint4 w4 = *(const uint4*)(Wt + (size_t)r*256 + k0 + kc*8);
            *(uint4*)(Wl + r*256 + ((kc ^ (r&7))<<4)) = w4;
        }
        __syncthreads();
        #pragma unroll
        for (int ks=0;ks<4;ks++){
            int kc = ks*4 + kg;
            int ra0 = wm*32+frow, ra1 = ra0+16;
            bf16x8 a0 = *(const bf16x8*)(Al + ra0*256 + ((kc ^ (ra0&7))<<4));
            bf16x8 a1 = *(const bf16x8*)(Al + ra1*256 + ((kc ^ (ra1&7))<<4));
            #pragma unroll
            for (int fn=0;fn<4;fn++){
                int rb = wn*64 + fn*16 + frow;
                bf16x8 bb = *(const bf16x8*)(Wl + rb*256 + ((kc ^ (rb&7))<<4));
                og[0][fn] = __builtin_amdgcn_mfma_f32_16x16x32_bf16(a0,bb,og[0][fn],0,0,0);
                og[1][fn] = __builtin_amdgcn_mfma_f32_16x16x32_bf16(a1,bb,og[1][fn],0,0,0);
            }
        }
    }
    __syncthreads();
    #pragma unroll
    for (int fm=0;fm<2;fm++)
    #pragma unroll
    for (int fn=0;fn<4;fn++){
        int gc = wn*64 + fn*16 + ccol;
        float bv = bias[gc];
        #pragma unroll
        for (int r=0;r<4;r++){
            int t = wm*32 + fm*16 + crow + r;
            size_t idx = (tok0+t)*DMODEL + gc;
            float v = og[fm][fn][r] + bv + bufx[idx];
            bufx[idx] = v;
            Ot[t*132 + gc] = v;
        }
    }
    if (doLN){
        __syncthreads();
        float w0 = lnw[lane*2], w1 = lnw[lane*2+1];
        float b0 = lnbias[lane*2], b1 = lnbias[lane*2+1];
        for (int r=0;r<16;r++){
            int row = wv*16 + r;
            float v0 = Ot[row*132 + lane*2], v1 = Ot[row*132 + lane*2+1];
            float s = v0+v1, q = v0*v0+v1*v1;
            #pragma unroll
            for (int o=32;o;o>>=1){ s += __shfl_xor(s,o); q += __shfl_xor(q,o); }
            float mu = s*(1.f/DMODEL);
            float inv = rsqrtf(q*(1.f/DMODEL) - mu*mu + 1e-5f);
            uint32_t pk = (uint32_t)f2bfu((v0-mu)*inv*w0 + b0) |
                          ((uint32_t)f2bfu((v1-mu)*inv*w1 + b1)<<16);
            ((uint32_t*)(lnb + (tok0+row)*DMODEL))[lane] = pk;
        }
    }
}

extern "C" void kernel_launch(void* const* d_in, const int* in_sizes, int n_in,
                              void* d_out, int out_size, void* d_ws, size_t ws_size,
                              hipStream_t stream)
{
    const float* x_in    = (const float*)d_in[0];
    const float* ln1_w   = (const float*)d_in[1];
    const float* ln1_b   = (const float*)d_in[2];
    const float* ln2_w   = (const float*)d_in[3];
    const float* ln2_b   = (const float*)d_in[4];
    const float* in_proj = (const float*)d_in[5];
    const float* conv_w  = (const float*)d_in[6];
    const float* conv_b  = (const float*)d_in[7];
    const float* dt_bias = (const float*)d_in[8];
    const float* A_log   = (const float*)d_in[9];
    const float* Dp      = (const float*)d_in[10];
    const float* out_proj= (const float*)d_in[11];
    const float* fc1_w   = (const float*)d_in[12];
    const float* fc1_b   = (const float*)d_in[13];
    const float* fc2_w   = (const float*)d_in[14];
    const float* fc2_b   = (const float*)d_in[15];

    float* ws = (float*)d_ws;
    float* buf_x    = ws;
    float* dtb      = buf_x  + (size_t)BLTOK*DMODEL;
    float* states   = dtb    + (size_t)BLTOK*4;
    float* Sbuf     = states + (size_t)BATCH*NHEADS*NCHUNK*HEADDIM*DSTATE;
    unsigned short* projb = (unsigned short*)(Sbuf + (size_t)BATCH*NHEADS*LSEQ);
    unsigned short* actb  = projb + (size_t)BLTOK*PROJS;
    unsigned short* lnb   = actb  + (size_t)BLTOK*DINNER;
    unsigned short* cbuf  = lnb   + (size_t)BLTOK*DMODEL;
    unsigned short* xBCb  = cbuf  + (size_t)BLTOK*DSTATE;
    unsigned short* Hp    = xBCb  + (size_t)BLTOK*CCH;
    unsigned short* wt_in = Hp    + (size_t)BATCH*NHEADS*NCHUNK*HEADDIM*DSTATE;
    unsigned short* wt_out= wt_in + (size_t)NLAYER*90112;
    unsigned short* wt_f1 = wt_out+ (size_t)NLAYER*32768;
    unsigned short* wt_f2 = wt_f1 + (size_t)NLAYER*65536;

    hipMemcpyAsync(buf_x, x_in, (size_t)BLTOK*DMODEL*sizeof(float),
                   hipMemcpyDeviceToDevice, stream);

    wconv_all_kernel<<<(NLAYER*221184+255)/256,256,0,stream>>>(
        in_proj, out_proj, fc1_w, fc2_w, wt_in, wt_out, wt_f1, wt_f2);

    ln_kernel<<<BLTOK/4,256,0,stream>>>(buf_x, ln1_w, ln1_b, lnb);

    for (int i=0;i<NLAYER;i++){
        gemm_inproj_kernel<<<dim3(11, BLTOK/64),256,0,stream>>>(
            lnb, wt_in + (size_t)i*90112, projb, dtb);
        conv_kernel<<<BLTOK/32,256,0,stream>>>(
            projb, conv_w+(size_t)i*KCONV*CCH, conv_b+(size_t)i*CCH, xBCb, cbuf);
        scan_intra_kernel<<<dim3(NCHUNK, BATCH),256,0,stream>>>(
            xBCb, dtb, dt_bias+i*NHEADS, A_log+i*NHEADS, Dp+i*NHEADS,
            actb, states, Sbuf);
        scan_inter_kernel<<<BATCH*NHEADS*16,256,0,stream>>>(states, Sbuf, Hp);
        apply_out_kernel<<<dim3(NCHUNK*2, BATCH),256,0,stream>>>(
            actb, Hp, cbuf, projb, Sbuf, wt_out + (size_t)i*32768,
            buf_x, lnb, ln2_w+i*DMODEL, ln2_b+i*DMODEL);
        fc1glu_kernel<<<dim3(4, BLTOK/64),256,0,stream>>>(
            lnb, wt_f1 + (size_t)i*65536, fc1_b+(size_t)i*FC1N, actb);
        fc2ln_kernel<<<BLTOK/64,256,0,stream>>>(
            actb, wt_f2 + (size_t)i*32768, fc2_b+i*DMODEL, buf_x, lnb,
            ln1_w+(i+1 < NLAYER ? (i+1)*DMODEL : 0),
            ln1_b+(i+1 < NLAYER ? (i+1)*DMODEL : 0),
            (i+1 < NLAYER) ? 1 : 0);
    }
    hipMemcpyAsync(d_out, buf_x, (size_t)BLTOK*DMODEL*sizeof(float),
                   hipMemcpyDeviceToDevice, stream);
}